// Round 6
// baseline (490.084 us; speedup 1.0000x reference)
//
#include <hip/hip_runtime.h>
#include <hip/hip_bf16.h>
#include <stddef.h>

// Problem constants (match reference setup_inputs)
#define N_NODES 100000
#define N_EDGES 20000
#define NNZ     1600000
#define DIM     128

// Edge LDS-histogram config
#define EH_BLOCKS  64
#define EH_THREADS 1024
#define EH_CHUNK   (NNZ / EH_BLOCKS)   // 25000 exactly

// Node LDS-histogram config (range-partitioned: 3 ranges of 33344 keys)
#define NB_N    64
#define NCHUNK  (NNZ / NB_N)           // 25000 exactly
#define NRANGE  33344                  // 3*33344 = 100032 >= 100000; 133.4 KB LDS

typedef short          bf16x8 __attribute__((ext_vector_type(8)));
typedef unsigned short u16x8  __attribute__((ext_vector_type(8)));
typedef float          f32x4  __attribute__((ext_vector_type(4)));
typedef float          f32x8  __attribute__((ext_vector_type(8)));

__device__ __forceinline__ unsigned short f2bf(float f) {
  union { float f; unsigned u; } c; c.f = f;
  unsigned r = c.u + 0x7FFFu + ((c.u >> 16) & 1u);   // round-to-nearest-even
  return (unsigned short)(r >> 16);
}

__device__ __forceinline__ f32x8 bf2f8(u16x8 v) {
  f32x8 r;
  #pragma unroll
  for (int i = 0; i < 8; ++i) {
    union { unsigned u; float f; } c; c.u = ((unsigned)v[i]) << 16;
    r[i] = c.f;
  }
  return r;
}

// ---------------- W fp32 -> bf16 ----------------
__global__ void convw_kernel(const float* __restrict__ W, unsigned short* __restrict__ Wb) {
  int i = blockIdx.x * 256 + threadIdx.x;
  if (i < DIM * DIM) Wb[i] = f2bf(W[i]);
}

// ---------------- GEMM: hb = bf16(x @ W^T + b) ----------------
// One wave: 16 rows x 128 cols. Fragment-row r of o-tile ot feeds W row (r*8+ot),
// so lane r owns 8 CONSECUTIVE output channels -> coalesced bf16x8 stores.
__global__ __launch_bounds__(256) void gemm_kernel(
    const float* __restrict__ x, const unsigned short* __restrict__ Wb,
    const float* __restrict__ bias, unsigned short* __restrict__ hb) {
  const int wid = threadIdx.x >> 6;
  const int l   = threadIdx.x & 63;
  const int n0  = (blockIdx.x * 4 + wid) * 16;
  if (n0 >= N_NODES) return;
  const int r  = l & 15;   // A-row within tile / B-fragment row
  const int kg = l >> 4;   // k-group (8 consecutive k per group)

  bf16x8 a[4];
  {
    const float* xr = x + (size_t)(n0 + r) * DIM + kg * 8;
    #pragma unroll
    for (int kc = 0; kc < 4; ++kc) {
      const float4* p = reinterpret_cast<const float4*>(xr + kc * 32);
      float4 f0 = p[0], f1 = p[1];
      bf16x8 av;
      av[0]=(short)f2bf(f0.x); av[1]=(short)f2bf(f0.y); av[2]=(short)f2bf(f0.z); av[3]=(short)f2bf(f0.w);
      av[4]=(short)f2bf(f1.x); av[5]=(short)f2bf(f1.y); av[6]=(short)f2bf(f1.z); av[7]=(short)f2bf(f1.w);
      a[kc] = av;
    }
  }

  f32x4 acc[8];
  #pragma unroll
  for (int ot = 0; ot < 8; ++ot) acc[ot] = (f32x4){0.f, 0.f, 0.f, 0.f};

  #pragma unroll
  for (int ot = 0; ot < 8; ++ot) {
    // permuted: o-tile ot, fragment row r <- W row (r*8 + ot)
    const unsigned short* wr = Wb + (size_t)(r * 8 + ot) * DIM + kg * 8;
    #pragma unroll
    for (int kc = 0; kc < 4; ++kc) {
      bf16x8 bfrag = *reinterpret_cast<const bf16x8*>(wr + kc * 32);
      acc[ot] = __builtin_amdgcn_mfma_f32_16x16x32_bf16(a[kc], bfrag, acc[ot], 0, 0, 0);
    }
  }

  // bias for this lane's 8 consecutive channels
  float bv[8];
  {
    const float4* bp = reinterpret_cast<const float4*>(bias + r * 8);
    float4 b0 = bp[0], b1 = bp[1];
    bv[0]=b0.x; bv[1]=b0.y; bv[2]=b0.z; bv[3]=b0.w;
    bv[4]=b1.x; bv[5]=b1.y; bv[6]=b1.z; bv[7]=b1.w;
  }

  // C/D: col(fragrow)=lane&15, row=(lane>>4)*4+reg  [m89]; col r of tile ot = channel r*8+ot
  #pragma unroll
  for (int j = 0; j < 4; ++j) {
    const int row = kg * 4 + j;
    u16x8 hv;
    #pragma unroll
    for (int ot = 0; ot < 8; ++ot) hv[ot] = f2bf(acc[ot][j] + bv[ot]);
    *reinterpret_cast<u16x8*>(&hb[(size_t)(n0 + row) * DIM + r * 8]) = hv;
  }
}

// ---------------- node histogram pass A: range-partitioned LDS histograms ----------------
__global__ __launch_bounds__(1024) void nhistA_kernel(
    const int* __restrict__ ni, int* __restrict__ bh) {
  __shared__ int hist[NRANGE];   // 133.4 KB
  const int base = blockIdx.x * NCHUNK;
  for (int p = 0; p < 3; ++p) {
    const int lo = p * NRANGE;
    for (int k = threadIdx.x; k < NRANGE; k += 1024) hist[k] = 0;
    __syncthreads();
    for (int i = base + threadIdx.x; i < base + NCHUNK; i += 1024) {
      int k = ni[i] - lo;
      if ((unsigned)k < NRANGE) atomicAdd(&hist[k], 1);
    }
    __syncthreads();
    const int hi = (lo + NRANGE <= N_NODES) ? NRANGE : (N_NODES - lo);
    for (int k = threadIdx.x; k < hi; k += 1024)
      bh[(size_t)(lo + k) * NB_N + blockIdx.x] = hist[k];
    __syncthreads();
  }
}

// ---------------- node scan: per-key serial scan over blocks -> bases + deg ----------------
__global__ void nscan_kernel(int* __restrict__ bh, int* __restrict__ deg) {
  int k = blockIdx.x * 256 + threadIdx.x;
  if (k >= N_NODES) return;
  int* p = bh + (size_t)k * NB_N;
  int s = 0;
  #pragma unroll 8
  for (int b = 0; b < NB_N; ++b) { int t = p[b]; p[b] = s; s += t; }
  deg[k] = s;
}

// ---------------- node pass B: rebuild LDS ranks + direct CSR scatter ----------------
__global__ __launch_bounds__(1024) void nscatterB_kernel(
    const int* __restrict__ ni, const int* __restrict__ ei,
    const int* __restrict__ bh, const int* __restrict__ off_n,
    int* __restrict__ csr_n2e) {
  __shared__ int hist[NRANGE];
  const int base = blockIdx.x * NCHUNK;
  for (int p = 0; p < 3; ++p) {
    const int lo = p * NRANGE;
    for (int k = threadIdx.x; k < NRANGE; k += 1024) hist[k] = 0;
    __syncthreads();
    for (int i = base + threadIdx.x; i < base + NCHUNK; i += 1024) {
      int n = ni[i];
      int k = n - lo;
      if ((unsigned)k < NRANGE) {
        int loc = atomicAdd(&hist[k], 1);
        csr_n2e[off_n[n] + bh[(size_t)n * NB_N + blockIdx.x] + loc] = ei[i];
      }
    }
    __syncthreads();
  }
}

// ---------------- edge histogram pass A: per-block LDS histograms ----------------
__global__ __launch_bounds__(EH_THREADS) void ehist_kernel(
    const int* __restrict__ ei, int* __restrict__ bh) {
  __shared__ int hist[N_EDGES];   // 80 KB
  for (int k = threadIdx.x; k < N_EDGES; k += EH_THREADS) hist[k] = 0;
  __syncthreads();
  const int base = blockIdx.x * EH_CHUNK;
  for (int i = base + threadIdx.x; i < base + EH_CHUNK; i += EH_THREADS)
    atomicAdd(&hist[ei[i]], 1);
  __syncthreads();
  for (int k = threadIdx.x; k < N_EDGES; k += EH_THREADS)
    bh[(size_t)k * EH_BLOCKS + blockIdx.x] = hist[k];
}

// ---------------- edge scan: per-key serial scan over blocks -> bases + totals ----------------
__global__ void escan_kernel(int* __restrict__ bh, int* __restrict__ deg_tmp) {
  int e = blockIdx.x * 256 + threadIdx.x;
  if (e >= N_EDGES) return;
  int* p = bh + (size_t)e * EH_BLOCKS;
  int base = 0;
  #pragma unroll 8
  for (int b = 0; b < EH_BLOCKS; ++b) { int t = p[b]; p[b] = base; base += t; }
  deg_tmp[e] = base;
}

// ---------------- edge pass B: rebuild LDS ranks + direct CSR scatter ----------------
__global__ __launch_bounds__(EH_THREADS) void escatter_kernel(
    const int* __restrict__ ei, const int* __restrict__ ni,
    const int* __restrict__ bh, const int* __restrict__ off_e,
    int* __restrict__ csr_e2n) {
  __shared__ int hist[N_EDGES];   // 80 KB
  for (int k = threadIdx.x; k < N_EDGES; k += EH_THREADS) hist[k] = 0;
  __syncthreads();
  const int base = blockIdx.x * EH_CHUNK;
  for (int i = base + threadIdx.x; i < base + EH_CHUNK; i += EH_THREADS) {
    int e = ei[i];
    int loc = atomicAdd(&hist[e], 1);
    csr_e2n[off_e[e] + bh[(size_t)e * EH_BLOCKS + blockIdx.x] + loc] = ni[i];
  }
}

// ---------------- hierarchical exclusive scan ----------------
__global__ void scan_block_kernel(const int* __restrict__ in, int* __restrict__ out,
                                  int* __restrict__ bsums, int n) {
  __shared__ int lds[512];
  const int tx = threadIdx.x;
  const int i  = blockIdx.x * blockDim.x + tx;
  int v = (i < n) ? in[i] : 0;
  int x = v;
  lds[tx] = x;
  __syncthreads();
  for (int off = 1; off < (int)blockDim.x; off <<= 1) {
    int t = (tx >= off) ? lds[tx - off] : 0;
    __syncthreads();
    x += t;
    lds[tx] = x;
    __syncthreads();
  }
  if (i < n) out[i] = x - v;                 // exclusive
  if (bsums && tx == (int)blockDim.x - 1) bsums[blockIdx.x] = x;  // total
}

__global__ void scan_add_kernel(int* __restrict__ out, const int* __restrict__ bsums, int n) {
  int i = blockIdx.x * blockDim.x + threadIdx.x;
  if (i < n) out[i] += bsums[blockIdx.x];
}

// ---------------- hop 1: m01b[e,:] = bf16( sum_{n in e} h[n,:] ) ----------------
// One 16-lane group owns one edge segment serially (no LDS, no syncs).
// 256 threads = 16 edges per block. 4-deep unroll for MLP.
__global__ __launch_bounds__(256) void hop1_kernel(
    const unsigned short* __restrict__ hb, const int* __restrict__ off_e,
    const int* __restrict__ csr_e2n, unsigned short* __restrict__ m01b) {
  const int e = blockIdx.x * 16 + (threadIdx.x >> 4);
  const int l = threadIdx.x & 15;
  if (e >= N_EDGES) return;
  const int s   = off_e[e];
  const int end = (e == N_EDGES - 1) ? NNZ : off_e[e + 1];

  f32x8 a0 = (f32x8){0.f,0.f,0.f,0.f,0.f,0.f,0.f,0.f};
  f32x8 a1 = a0, a2 = a0, a3 = a0;
  int j = s;
  for (; j + 3 < end; j += 4) {
    const int n0 = csr_e2n[j + 0];
    const int n1 = csr_e2n[j + 1];
    const int n2 = csr_e2n[j + 2];
    const int n3 = csr_e2n[j + 3];
    u16x8 v0 = *reinterpret_cast<const u16x8*>(&hb[(size_t)n0 * DIM + l * 8]);
    u16x8 v1 = *reinterpret_cast<const u16x8*>(&hb[(size_t)n1 * DIM + l * 8]);
    u16x8 v2 = *reinterpret_cast<const u16x8*>(&hb[(size_t)n2 * DIM + l * 8]);
    u16x8 v3 = *reinterpret_cast<const u16x8*>(&hb[(size_t)n3 * DIM + l * 8]);
    a0 += bf2f8(v0); a1 += bf2f8(v1); a2 += bf2f8(v2); a3 += bf2f8(v3);
  }
  for (; j < end; ++j) {
    const int n = csr_e2n[j];
    a0 += bf2f8(*reinterpret_cast<const u16x8*>(&hb[(size_t)n * DIM + l * 8]));
  }
  f32x8 r = (a0 + a1) + (a2 + a3);
  u16x8 o;
  #pragma unroll
  for (int i = 0; i < 8; ++i) o[i] = f2bf(r[i]);
  *reinterpret_cast<u16x8*>(&m01b[(size_t)e * DIM + l * 8]) = o;
}

// ---------------- hop 2 + finalize: out[n,:] = h[n,:] + mean_{e ni n} m01[e,:] ----------------
// One 16-lane group owns one node segment serially. 256 threads = 16 nodes/block.
__global__ __launch_bounds__(256) void hop2_kernel(
    const unsigned short* __restrict__ hb, const int* __restrict__ off_n,
    const int* __restrict__ csr_n2e, const unsigned short* __restrict__ m01b,
    float* __restrict__ out) {
  const int n = blockIdx.x * 16 + (threadIdx.x >> 4);
  const int l = threadIdx.x & 15;
  if (n >= N_NODES) return;
  const int s   = off_n[n];
  const int end = (n == N_NODES - 1) ? NNZ : off_n[n + 1];
  const int cnt = end - s;

  f32x8 a0 = (f32x8){0.f,0.f,0.f,0.f,0.f,0.f,0.f,0.f};
  f32x8 a1 = a0;
  int j = s;
  for (; j + 1 < end; j += 2) {
    const int e0 = csr_n2e[j + 0];
    const int e1 = csr_n2e[j + 1];
    u16x8 v0 = *reinterpret_cast<const u16x8*>(&m01b[(size_t)e0 * DIM + l * 8]);
    u16x8 v1 = *reinterpret_cast<const u16x8*>(&m01b[(size_t)e1 * DIM + l * 8]);
    a0 += bf2f8(v0); a1 += bf2f8(v1);
  }
  if (j < end) {
    const int e = csr_n2e[j];
    a0 += bf2f8(*reinterpret_cast<const u16x8*>(&m01b[(size_t)e * DIM + l * 8]));
  }
  f32x8 r  = a0 + a1;
  f32x8 hv = bf2f8(*reinterpret_cast<const u16x8*>(&hb[(size_t)n * DIM + l * 8]));
  const float inv = 1.0f / (float)(cnt > 0 ? cnt : 1);
  f32x8 o = hv + r * inv;
  float* op = &out[(size_t)n * DIM + l * 8];
  *reinterpret_cast<f32x4*>(op)     = (f32x4){o[0], o[1], o[2], o[3]};
  *reinterpret_cast<f32x4*>(op + 4) = (f32x4){o[4], o[5], o[6], o[7]};
}

extern "C" void kernel_launch(void* const* d_in, const int* in_sizes, int n_in,
                              void* d_out, int out_size, void* d_ws, size_t ws_size,
                              hipStream_t stream) {
  const float* x    = (const float*)d_in[0];
  const float* W    = (const float*)d_in[1];
  const float* bias = (const float*)d_in[2];
  const int*   ni   = (const int*)d_in[3];
  const int*   ei   = (const int*)d_in[4];
  float* out = (float*)d_out;

  // ---- workspace carve ----
  char* ws = (char*)d_ws;
  size_t o = 0;
  auto carve = [&](size_t bytes) -> char* {
    char* p = ws + o;
    o = (o + bytes + 255) & ~(size_t)255;
    return p;
  };
  unsigned short* hb      = (unsigned short*)carve((size_t)N_NODES * DIM * 2);       // 25.6 MB
  unsigned short* m01b    = (unsigned short*)carve((size_t)N_EDGES * DIM * 2);       // 5.12 MB
  int*            csr_e2n = (int*)           carve((size_t)NNZ * 4);                 // 6.4 MB
  int*            csr_n2e = (int*)           carve((size_t)NNZ * 4);                 // 6.4 MB
  unsigned short* Wb      = (unsigned short*)carve((size_t)DIM * DIM * 2);           // 32 KB
  int*            bh_e    = (int*)           carve((size_t)N_EDGES * EH_BLOCKS * 4); // 5.12 MB
  int*            bh_n    = (int*)           carve((size_t)N_NODES * NB_N * 4);      // 25.6 MB
  int*            deg_n   = (int*)           carve((size_t)N_NODES * 4);             // 400 KB
  int*            deg_tmp = (int*)           carve((size_t)N_EDGES * 4);
  int*            off_n   = (int*)           carve((size_t)N_NODES * 4);
  int*            off_e   = (int*)           carve((size_t)N_EDGES * 4);
  int*            bsums   = (int*)           carve(512 * 4);
  (void)ws_size; (void)in_sizes; (void)n_in; (void)out_size;

  // ---- W -> bf16, GEMM ----
  convw_kernel<<<(DIM * DIM + 255) / 256, 256, 0, stream>>>(W, Wb);
  gemm_kernel<<<(N_NODES / 16 + 3) / 4, 256, 0, stream>>>(x, Wb, bias, hb);

  // ---- edge side: hist -> per-key scan -> off scan -> direct scatter ----
  ehist_kernel<<<EH_BLOCKS, EH_THREADS, 0, stream>>>(ei, bh_e);
  escan_kernel<<<(N_EDGES + 255) / 256, 256, 0, stream>>>(bh_e, deg_tmp);
  {
    int nbl_e = (N_EDGES + 255) / 256;   // 79
    scan_block_kernel<<<nbl_e, 256, 0, stream>>>(deg_tmp, off_e, bsums, N_EDGES);
    scan_block_kernel<<<1, 512, 0, stream>>>(bsums, bsums, nullptr, nbl_e);
    scan_add_kernel<<<nbl_e, 256, 0, stream>>>(off_e, bsums, N_EDGES);
  }
  escatter_kernel<<<EH_BLOCKS, EH_THREADS, 0, stream>>>(ei, ni, bh_e, off_e, csr_e2n);

  // ---- node side: range-partitioned LDS hist -> scans -> direct scatter ----
  nhistA_kernel<<<NB_N, 1024, 0, stream>>>(ni, bh_n);
  nscan_kernel<<<(N_NODES + 255) / 256, 256, 0, stream>>>(bh_n, deg_n);
  {
    int nbl_n = (N_NODES + 255) / 256;   // 391
    scan_block_kernel<<<nbl_n, 256, 0, stream>>>(deg_n, off_n, bsums, N_NODES);
    scan_block_kernel<<<1, 512, 0, stream>>>(bsums, bsums, nullptr, nbl_n);
    scan_add_kernel<<<nbl_n, 256, 0, stream>>>(off_n, bsums, N_NODES);
  }
  nscatterB_kernel<<<NB_N, 1024, 0, stream>>>(ni, ei, bh_n, off_n, csr_n2e);

  // ---- hops ----
  hop1_kernel<<<(N_EDGES + 15) / 16, 256, 0, stream>>>(hb, off_e, csr_e2n, m01b);
  hop2_kernel<<<(N_NODES + 15) / 16, 256, 0, stream>>>(hb, off_n, csr_n2e, m01b, out);
}